// Round 2
// baseline (849.965 us; speedup 1.0000x reference)
//
#include <hip/hip_runtime.h>

#define B_TOT 65536
#define NPART 6
#define DD 41
#define FS 44          // padded row stride (floats), 16B-aligned rows
#define KDET 4

// ---- LDS float-offset layout ----
#define OFF_F    0          // 12 * 41 * 44 = 21648
#define OFF_W1   21648      // 640
#define OFF_B1   22288      // 64
#define OFF_W2T  22352      // 64*68 = 4352  (W2 transposed, row-padded to 68)
#define OFF_B2   26704      // 64
#define OFF_W3T  26768      // 32*68 = 2176  (W3 transposed, row-padded to 68)
#define OFF_B3   28944      // 32
#define OFF_SE   28976      // 16
#define OFF_SC   28992      // per-wave scratch, 864 floats each, 8 waves
#define SC_STRIDE 864
#define LDS_FLOATS (28992 + 8*864)   // 35904 floats = 143616 B

// pair enumeration p=0..14 : (n,m) lexicographic n<m
__device__ const int PN_TAB[15] = {0,0,0,0,0,1,1,1,1,2,2,2,3,3,4};
__device__ const int PM_TAB[15] = {1,2,3,4,5,2,3,4,5,3,4,5,4,5,5};
// matchings -> 3 pair indices; sign alternates +,-,+,...
__device__ const int M1_TAB[15] = {0,0,0,1,1,1,2,2,2,3,3,3,4,4,4};
__device__ const int M2_TAB[15] = {9,10,11,6,7,8,5,7,8,5,6,8,5,6,7};
__device__ const int M3_TAB[15] = {14,13,12,14,13,12,14,11,10,13,11,9,12,10,9};

__global__ __launch_bounds__(512, 2)
void pfaff_kernel(const float* __restrict__ x, const int* __restrict__ spin,
                  const float* __restrict__ se, const float* __restrict__ W1,
                  const float* __restrict__ b1, const float* __restrict__ W2,
                  const float* __restrict__ b2, const float* __restrict__ W3,
                  const float* __restrict__ b3, const float* __restrict__ Phf,
                  const float* __restrict__ dFud, const float* __restrict__ dFuu,
                  const float* __restrict__ dFdd, const float* __restrict__ wdet,
                  float* __restrict__ out)
{
    __shared__ __align__(16) float lds[LDS_FLOATS];
    float* Fl   = lds + OFF_F;
    float* W1l  = lds + OFF_W1;
    float* b1l  = lds + OFF_B1;
    float* W2tl = lds + OFF_W2T;
    float* b2l  = lds + OFF_B2;
    float* W3tl = lds + OFF_W3T;
    float* b3l  = lds + OFF_B3;
    float* sel  = lds + OFF_SE;

    const int tid = threadIdx.x;

    // ---- stage combined F matrices (pads zeroed): sk = s*4+k ; s: 0=uu 1=dd 2=ud
    for (int idx = tid; idx < 12*DD*FS; idx += blockDim.x) {
        int sk = idx / (DD*FS);
        int r  = idx - sk*(DD*FS);
        int d0 = r / FS;
        int e0 = r - d0*FS;
        float v = 0.f;
        if (e0 < DD) {
            int s = sk >> 2, k = sk & 3;
            const float* src = (s==0) ? dFuu : (s==1) ? dFdd : dFud;
            v = src[(k*DD + d0)*DD + e0];
            if (s < 2)  v = 0.01f * (v - src[(k*DD + e0)*DD + d0]);
            else      { v *= 0.01f; if (k == 0) v += Phf[d0*DD + e0]; }
        }
        Fl[idx] = v;
    }
    // ---- stage weights (W2/W3 transposed with pad-68 rows; pads zeroed) ----
    for (int i = tid; i < 640;  i += blockDim.x) W1l[i] = W1[i];
    for (int i = tid; i < 64;   i += blockDim.x) b1l[i] = b1[i];
    for (int idx = tid; idx < 64*68; idx += blockDim.x) {
        int j = idx / 68, i = idx - j*68;
        W2tl[idx] = (i < 64) ? W2[i*64 + j] : 0.f;
    }
    for (int i = tid; i < 64;   i += blockDim.x) b2l[i] = b2[i];
    for (int idx = tid; idx < 32*68; idx += blockDim.x) {
        int j = idx / 68, i = idx - j*68;
        W3tl[idx] = (i < 64) ? W3[i*32 + j] : 0.f;
    }
    for (int i = tid; i < 32;   i += blockDim.x) b3l[i] = b3[i];
    for (int i = tid; i < 16;   i += blockDim.x) sel[i] = se[i];

    const int wave = tid >> 6, lane = tid & 63;
    float* sc  = lds + OFF_SC + wave*SC_STRIDE;
    float* t_s = sc;          // [0,528): 12 rows * 44 (time-shares with inp/h1)
    float* inp = sc;          // [0,60)
    float* h1  = sc + 64;     // [64,448)
    float* hA  = sc + 528;    // [528,792): 6 rows * 44
    float* As  = sc + 792;    // [792,852): 4*15

    // zero per-wave scratch once (kills any stale-LDS dependence)
    for (int i = lane; i < SC_STRIDE; i += 64) sc[i] = 0.f;
    __syncthreads();

    int pn=0, pm=0, m1i=0, m2i=0, m3i=0;
    if (lane < 15) { pn=PN_TAB[lane]; pm=PM_TAB[lane];
                     m1i=M1_TAB[lane]; m2i=M2_TAB[lane]; m3i=M3_TAB[lane]; }
    float wreg[4];
    #pragma unroll
    for (int k=0;k<4;k++) wreg[k] = wdet[k];

    const int ebase = ((int)blockIdx.x * 8 + wave) * 16;
    for (int ei = 0; ei < 16; ++ei) {
        const int e = ebase + ei;

        // ---- P0: particle data -> inp rows + Phi (hA rows 0..8, pads zeroed) ----
        int s_n = 0; float xx = 0.f, xy = 0.f;
        if (lane < NPART) {
            float2 xv = *(const float2*)(x + (size_t)(e*NPART + lane)*2);
            xx = xv.x; xy = xv.y;
            s_n = spin[e*NPART + lane];
        }
        unsigned long long dn64 = __ballot(lane < NPART && s_n == 1);
        const unsigned dn  = (unsigned)dn64 & 63u;
        const unsigned upm = (~dn) & 63u;

        if (lane < NPART) {
            inp[lane*10 + 0] = xx;
            inp[lane*10 + 1] = xy;
            float ex = __expf(-0.5f*(xx*xx));
            float px0 = 0.7511255444649425f * ex;
            float px1 = 1.4142135623730951f * xx * px0;
            float px2 = fmaf(xx, px1, -0.7071067811865476f * px0);
            float ey = __expf(-0.5f*(xy*xy));
            float py0 = 0.7511255444649425f * ey;
            float py1 = 1.4142135623730951f * xy * py0;
            float py2 = fmaf(xy, py1, -0.7071067811865476f * py0);
            float* hr = hA + lane*FS;
            hr[0]=px0*py0; hr[1]=px0*py1; hr[2]=px0*py2;
            hr[3]=px1*py0; hr[4]=px1*py1; hr[5]=px1*py2;
            hr[6]=px2*py0; hr[7]=px2*py1; hr[8]=px2*py2;
            hr[41]=0.f; hr[42]=0.f; hr[43]=0.f;
        }
        {
            int n8 = lane >> 3, j8 = lane & 7;
            int spn = __shfl(s_n, n8);
            if (lane < 48) inp[n8*10 + 2 + j8] = sel[spn*8 + j8];
        }
        __syncthreads();

        // ---- L1 (10 -> 64), lane = output j ----
        float acc[6];
        #pragma unroll
        for (int n=0;n<6;n++) acc[n] = b1l[lane];
        #pragma unroll
        for (int i=0;i<10;i++){
            float wv = W1l[i*64 + lane];
            #pragma unroll
            for (int n=0;n<6;n++) acc[n] = fmaf(inp[n*10+i], wv, acc[n]);
        }
        #pragma unroll
        for (int n=0;n<6;n++){
            float v = acc[n];
            h1[n*64 + lane] = v / (1.f + __expf(-v));
        }
        __syncthreads();

        // ---- L2 (64 -> 64): reads, barrier, writes ----
        #pragma unroll
        for (int n=0;n<6;n++) acc[n] = b2l[lane];
        #pragma unroll
        for (int i4=0;i4<16;i4++){
            float4 w4 = *(const float4*)(W2tl + lane*68 + i4*4);
            #pragma unroll
            for (int n=0;n<6;n++){
                float4 h4 = *(const float4*)(h1 + n*64 + i4*4);
                acc[n] = fmaf(w4.x,h4.x,acc[n]); acc[n] = fmaf(w4.y,h4.y,acc[n]);
                acc[n] = fmaf(w4.z,h4.z,acc[n]); acc[n] = fmaf(w4.w,h4.w,acc[n]);
            }
        }
        __syncthreads();
        #pragma unroll
        for (int n=0;n<6;n++){
            float v = acc[n];
            h1[n*64 + lane] = v / (1.f + __expf(-v));
        }
        __syncthreads();

        // ---- L3 (64 -> 32): lanes split into 2 halves of particles ----
        {
            int j2 = lane & 31, hf = lane >> 5;
            float a3[3];
            #pragma unroll
            for (int nn=0;nn<3;nn++) a3[nn] = b3l[j2];
            #pragma unroll
            for (int i4=0;i4<16;i4++){
                float4 w4 = *(const float4*)(W3tl + j2*68 + i4*4);
                #pragma unroll
                for (int nn=0;nn<3;nn++){
                    float4 h4 = *(const float4*)(h1 + (hf*3+nn)*64 + i4*4);
                    a3[nn]=fmaf(w4.x,h4.x,a3[nn]); a3[nn]=fmaf(w4.y,h4.y,a3[nn]);
                    a3[nn]=fmaf(w4.z,h4.z,a3[nn]); a3[nn]=fmaf(w4.w,h4.w,a3[nn]);
                }
            }
            #pragma unroll
            for (int nn=0;nn<3;nn++) hA[(hf*3+nn)*FS + 9 + j2] = a3[nn];
        }
        __syncthreads();

        // ---- Pfaffian bilinear forms ----
        const int d = (lane < DD) ? lane : (DD-1);

        for (int k = 0; k < KDET; ++k) {
            // three uniform passes: (bank0=uu -> t[m] for up m), (bank1=dd -> t[m] for dn m),
            // (bank2=ud -> t[6+m] for dn m). Lanes 41..43 store 0 (pad zeroing).
            #pragma unroll
            for (int pass=0; pass<3; ++pass) {
                const int bank = (pass==0) ? 0 : (pass==1) ? 1 : 2;
                const unsigned mk = (pass==0) ? upm : dn;
                const int dst0 = (pass==2) ? 6 : 0;
                const float* Fr = Fl + ((bank*4 + k)*DD + d)*FS;
                float4 fr[11];
                #pragma unroll
                for (int q=0;q<11;q++) fr[q] = *(const float4*)(Fr + q*4);
                for (int m=0;m<6;m++){
                    if (!((mk>>m)&1)) continue;
                    const float* hm = hA + m*FS;
                    float a0=0.f,a1=0.f,a2=0.f,a3=0.f;
                    #pragma unroll
                    for (int q=0;q<11;q++){
                        float4 h4 = *(const float4*)(hm + q*4);
                        a0 = fmaf(fr[q].x,h4.x,a0); a1 = fmaf(fr[q].y,h4.y,a1);
                        a2 = fmaf(fr[q].z,h4.z,a2); a3 = fmaf(fr[q].w,h4.w,a3);
                    }
                    float t = (a0+a1)+(a2+a3);
                    int row = dst0 + m;
                    if (lane < DD)      t_s[row*FS + lane] = t;
                    else if (lane < FS) t_s[row*FS + lane] = 0.f;
                }
            }
            __syncthreads();

            // ---- A[k][pair] : lanes 0..14 ----
            if (lane < 15) {
                int sn = (int)((dn>>pn)&1), sm = (int)((dn>>pm)&1);
                int hrow, trow; float sg;
                if (sn == sm)      { hrow = pn; trow = pm;     sg =  1.f; }
                else if (sn == 0)  { hrow = pn; trow = 6 + pm; sg =  1.f; }   // n up, m dn
                else               { hrow = pm; trow = 6 + pn; sg = -1.f; }   // n dn, m up
                const float* hp = hA  + hrow*FS;
                const float* tp = t_s + trow*FS;
                float a0=0.f,a1=0.f,a2=0.f,a3=0.f;
                #pragma unroll
                for (int q=0;q<11;q++){
                    float4 hv = *(const float4*)(hp + q*4);
                    float4 tv = *(const float4*)(tp + q*4);
                    a0 = fmaf(hv.x,tv.x,a0); a1 = fmaf(hv.y,tv.y,a1);
                    a2 = fmaf(hv.z,tv.z,a2); a3 = fmaf(hv.w,tv.w,a3);
                }
                As[k*15 + lane] = sg * ((a0+a1)+(a2+a3));
            }
            __syncthreads();
        }

        // ---- pfaffian sum over 15 matchings, 4 determinants ----
        float total = 0.f;
        #pragma unroll
        for (int k=0;k<KDET;k++){
            float term = 0.f;
            if (lane < 15) {
                float p = As[k*15+m1i] * As[k*15+m2i] * As[k*15+m3i];
                term = (lane & 1) ? -p : p;
            }
            term += __shfl_xor(term, 1);
            term += __shfl_xor(term, 2);
            term += __shfl_xor(term, 4);
            term += __shfl_xor(term, 8);
            total = fmaf(wreg[k], term, total);
        }
        if (lane == 0) {
            float sgn = (total > 0.f) ? 1.f : ((total < 0.f) ? -1.f : 1.f);
            float la  = 0.5f * logf(fmaf(total, total, 1e-60f));
            out[e]         = sgn;
            out[B_TOT + e] = la;
        }
        __syncthreads();
    }
}

extern "C" void kernel_launch(void* const* d_in, const int* in_sizes, int n_in,
                              void* d_out, int out_size, void* d_ws, size_t ws_size,
                              hipStream_t stream)
{
    const float* x    = (const float*)d_in[0];
    const int*   spin = (const int*)  d_in[1];
    const float* se   = (const float*)d_in[2];
    const float* W1   = (const float*)d_in[3];
    const float* b1   = (const float*)d_in[4];
    const float* W2   = (const float*)d_in[5];
    const float* b2   = (const float*)d_in[6];
    const float* W3   = (const float*)d_in[7];
    const float* b3   = (const float*)d_in[8];
    const float* Phf  = (const float*)d_in[9];
    const float* dFud = (const float*)d_in[10];
    const float* dFuu = (const float*)d_in[11];
    const float* dFdd = (const float*)d_in[12];
    const float* w    = (const float*)d_in[13];
    float* out = (float*)d_out;

    hipLaunchKernelGGL(pfaff_kernel, dim3(512), dim3(512), 0, stream,
                       x, spin, se, W1, b1, W2, b2, W3, b3, Phf,
                       dFud, dFuu, dFdd, w, out);
}

// Round 3
// 582.223 us; speedup vs baseline: 1.4599x; 1.4599x over previous
//
#include <hip/hip_runtime.h>

#define B_TOT 65536
#define RS 44            // padded row stride (floats) for h / t rows
#define KDET 4

// ---- LDS float-offset layout (weights + per-wave scratch) ----
#define OFF_W1   0        // 640
#define OFF_B1   640      // 64
#define OFF_W2T  704      // 64*68 = 4352 (W2 transposed, rows padded to 68)
#define OFF_B2   5056     // 64
#define OFF_W3T  5120     // 32*68 = 2176 (W3 transposed, rows padded to 68)
#define OFF_B3   7296     // 32
#define OFF_SE   7328     // 16
#define OFF_SC   7344     // per-wave scratch
#define SC_STRIDE 1584    // t_s [0,1056) (time-shared with inp[0,120)+h1[128,896)) | hA [1056,1584)
#define LDS_FLOATS (7344 + 8*1584)   // 20016 floats = 80064 B  -> 2 blocks/CU

// pair enumeration p=0..14 : (n,m) lexicographic n<m
__device__ const int PN_TAB[15] = {0,0,0,0,0,1,1,1,1,2,2,2,3,3,4};
__device__ const int PM_TAB[15] = {1,2,3,4,5,2,3,4,5,3,4,5,4,5,5};
// matchings -> 3 pair indices; sign alternates +,-,+,...
__device__ const int M1_TAB[15] = {0,0,0,1,1,1,2,2,2,3,3,3,4,4,4};
__device__ const int M2_TAB[15] = {9,10,11,6,7,8,5,7,8,5,6,8,5,6,7};
__device__ const int M3_TAB[15] = {14,13,12,14,13,12,14,11,10,13,11,9,12,10,9};

// Build F~ in swizzled layout: wsF[(sk*11 + c)*64 + d] = float4 { F~[sk][d][4c+j] }j=0..3
// sk = s*4+k ; s: 0=uu 1=dd 2=ud. Rows d>=41 and cols e>=41 zero-padded.
__global__ void prep_F(const float* __restrict__ dFud, const float* __restrict__ dFuu,
                       const float* __restrict__ dFdd, const float* __restrict__ Phf,
                       float4* __restrict__ wsF)
{
    int t = blockIdx.x * 256 + threadIdx.x;
    if (t >= 12*11*64) return;
    int d  = t & 63;
    int c  = (t >> 6) % 11;
    int sk = t / (11*64);
    int s = sk >> 2, k = sk & 3;
    const float* src = (s==0) ? dFuu : (s==1) ? dFdd : dFud;
    float v[4];
    #pragma unroll
    for (int j=0;j<4;j++){
        int e = 4*c + j;
        float r = 0.f;
        if (d < 41 && e < 41) {
            if (s < 2) r = 0.01f * (src[(k*41+d)*41+e] - src[(k*41+e)*41+d]);
            else     { r = 0.01f *  src[(k*41+d)*41+e]; if (k==0) r += Phf[d*41+e]; }
        }
        v[j] = r;
    }
    wsF[t] = make_float4(v[0],v[1],v[2],v[3]);
}

__global__ __launch_bounds__(512, 4)
void pfaff_main(const float* __restrict__ x, const int* __restrict__ spin,
                const float* __restrict__ se, const float* __restrict__ W1,
                const float* __restrict__ b1, const float* __restrict__ W2,
                const float* __restrict__ b2, const float* __restrict__ W3,
                const float* __restrict__ b3, const float* __restrict__ wdet,
                const float4* __restrict__ wsF, float* __restrict__ out)
{
    __shared__ __align__(16) float lds[LDS_FLOATS];
    float* W1l  = lds + OFF_W1;
    float* b1l  = lds + OFF_B1;
    float* W2tl = lds + OFF_W2T;
    float* b2l  = lds + OFF_B2;
    float* W3tl = lds + OFF_W3T;
    float* b3l  = lds + OFF_B3;
    float* sel  = lds + OFF_SE;

    const int tid = threadIdx.x;

    // ---- stage weights (transposed W2/W3, pad-68 rows, pads zeroed) ----
    for (int i = tid; i < 640;  i += blockDim.x) W1l[i] = W1[i];
    for (int i = tid; i < 64;   i += blockDim.x) b1l[i] = b1[i];
    for (int idx = tid; idx < 64*68; idx += blockDim.x) {
        int j = idx / 68, i = idx - j*68;
        W2tl[idx] = (i < 64) ? W2[i*64 + j] : 0.f;
    }
    for (int i = tid; i < 64;   i += blockDim.x) b2l[i] = b2[i];
    for (int idx = tid; idx < 32*68; idx += blockDim.x) {
        int j = idx / 68, i = idx - j*68;
        W3tl[idx] = (i < 64) ? W3[i*32 + j] : 0.f;
    }
    for (int i = tid; i < 32;   i += blockDim.x) b3l[i] = b3[i];
    for (int i = tid; i < 16;   i += blockDim.x) sel[i] = se[i];

    const int wave = tid >> 6, lane = tid & 63;
    float* sc  = lds + OFF_SC + wave*SC_STRIDE;
    float* t_s = sc;            // [0,1056): 2 elem * 12 rows * 44
    float* inp = sc;            // [0,120)   (time-shared)
    float* h1  = sc + 128;      // [128,896) (time-shared)
    float* hA  = sc + 1056;     // [1056,1584): 2 elem * 6 rows * 44

    for (int i = lane; i < SC_STRIDE; i += 64) sc[i] = 0.f;   // kill stale-LDS dependence
    __syncthreads();

    int pn=0, pm=0, m1i=0, m2i=0, m3i=0;
    const int p = lane & 31, g = lane >> 5;
    if (p < 15) { pn=PN_TAB[p]; pm=PM_TAB[p];
                  m1i=M1_TAB[p]; m2i=M2_TAB[p]; m3i=M3_TAB[p]; }
    float wreg[4];
    #pragma unroll
    for (int k=0;k<4;k++) wreg[k] = wdet[k];

    const int d = lane;   // bilinear row index; rows >= 41 are zero in wsF

    const int ebase = ((int)blockIdx.x * 8 + wave) * 16;
    #pragma unroll 1
    for (int pi = 0; pi < 8; ++pi) {
        const int e0 = ebase + pi*2;

        // ---- P0: particle data for 2 elements -> inp rows + Phi ----
        int s_n = 0; float xx = 0.f, xy = 0.f;
        if (lane < 12) {
            int gg = lane >= 6;
            int eg = e0 + gg;
            int n  = lane - gg*6;
            float2 xv = *(const float2*)(x + (size_t)(eg*6 + n)*2);
            xx = xv.x; xy = xv.y;
            s_n = spin[eg*6 + n];
        }
        unsigned long long bal = __ballot(lane < 12 && s_n == 1);
        const unsigned dn0 = (unsigned)bal & 63u;
        const unsigned dn1 = (unsigned)(bal >> 6) & 63u;

        if (lane < 12) {
            inp[lane*10 + 0] = xx;
            inp[lane*10 + 1] = xy;
            float ex = __expf(-0.5f*(xx*xx));
            float px0 = 0.7511255444649425f * ex;
            float px1 = 1.4142135623730951f * xx * px0;
            float px2 = fmaf(xx, px1, -0.7071067811865476f * px0);
            float ey = __expf(-0.5f*(xy*xy));
            float py0 = 0.7511255444649425f * ey;
            float py1 = 1.4142135623730951f * xy * py0;
            float py2 = fmaf(xy, py1, -0.7071067811865476f * py0);
            float* hr = hA + lane*RS;
            hr[0]=px0*py0; hr[1]=px0*py1; hr[2]=px0*py2;
            hr[3]=px1*py0; hr[4]=px1*py1; hr[5]=px1*py2;
            hr[6]=px2*py0; hr[7]=px2*py1; hr[8]=px2*py2;
            hr[41]=0.f; hr[42]=0.f; hr[43]=0.f;
        }
        #pragma unroll
        for (int rep=0; rep<2; ++rep) {      // spin-embed: 12 rows * 8
            int idx = rep*64 + lane;
            int r = idx >> 3, j8 = idx & 7;
            int spn = __shfl(s_n, r < 12 ? r : 0);
            if (idx < 96) inp[r*10 + 2 + j8] = sel[spn*8 + j8];
        }
        __syncthreads();

        // ---- L1 (10 -> 64), lane = hidden j, 12 particle-rows ----
        float acc[12];
        #pragma unroll
        for (int r=0;r<12;r++) acc[r] = b1l[lane];
        #pragma unroll
        for (int i=0;i<10;i++){
            float wv = W1l[i*64 + lane];
            #pragma unroll
            for (int r=0;r<12;r++) acc[r] = fmaf(inp[r*10+i], wv, acc[r]);
        }
        #pragma unroll
        for (int r=0;r<12;r++){
            float v = acc[r];
            h1[r*64 + lane] = v / (1.f + __expf(-v));
        }
        __syncthreads();

        // ---- L2 (64 -> 64) ----
        #pragma unroll
        for (int r=0;r<12;r++) acc[r] = b2l[lane];
        #pragma unroll
        for (int i4=0;i4<16;i4++){
            float4 w4 = *(const float4*)(W2tl + lane*68 + i4*4);
            #pragma unroll
            for (int r=0;r<12;r++){
                float4 h4 = *(const float4*)(h1 + r*64 + i4*4);
                acc[r]=fmaf(w4.x,h4.x,acc[r]); acc[r]=fmaf(w4.y,h4.y,acc[r]);
                acc[r]=fmaf(w4.z,h4.z,acc[r]); acc[r]=fmaf(w4.w,h4.w,acc[r]);
            }
        }
        __syncthreads();
        #pragma unroll
        for (int r=0;r<12;r++){
            float v = acc[r];
            h1[r*64 + lane] = v / (1.f + __expf(-v));
        }
        __syncthreads();

        // ---- L3 (64 -> 32): half-wave per element ----
        {
            int j2 = lane & 31, hf = lane >> 5;
            float a3[6];
            #pragma unroll
            for (int rr=0;rr<6;rr++) a3[rr] = b3l[j2];
            #pragma unroll
            for (int i4=0;i4<16;i4++){
                float4 w4 = *(const float4*)(W3tl + j2*68 + i4*4);
                #pragma unroll
                for (int rr=0;rr<6;rr++){
                    float4 h4 = *(const float4*)(h1 + (hf*6+rr)*64 + i4*4);
                    a3[rr]=fmaf(w4.x,h4.x,a3[rr]); a3[rr]=fmaf(w4.y,h4.y,a3[rr]);
                    a3[rr]=fmaf(w4.z,h4.z,a3[rr]); a3[rr]=fmaf(w4.w,h4.w,a3[rr]);
                }
            }
            #pragma unroll
            for (int rr=0;rr<6;rr++) hA[(hf*6+rr)*RS + 9 + j2] = a3[rr];
        }
        __syncthreads();

        // ---- bilinear + pfaffian ----
        float total = 0.f;
        #pragma unroll 1
        for (int k = 0; k < KDET; ++k) {
            // 3 passes: uu (up m), dd (dn m), ud (dn m -> rows 6+m)
            #pragma unroll 1
            for (int pass=0; pass<3; ++pass) {
                const float4* Fp = wsF + (size_t)(pass*4 + k)*(11*64) + d;
                float4 fr[11];
                #pragma unroll
                for (int c=0;c<11;c++) fr[c] = Fp[c*64];
                #pragma unroll
                for (int gg=0; gg<2; ++gg) {
                    unsigned dng = gg ? dn1 : dn0;
                    unsigned mk  = pass ? dng : ((~dng) & 63u);
                    int base = gg*12 + (pass==2 ? 6 : 0);
                    for (int m=0;m<6;m++) {
                        if (!((mk>>m)&1)) continue;
                        const float4* hm4 = (const float4*)(hA + (gg*6+m)*RS);
                        float a0=0.f,a1=0.f,a2=0.f,a3v=0.f;
                        #pragma unroll
                        for (int q=0;q<11;q++){
                            float4 h4 = hm4[q];
                            a0=fmaf(fr[q].x,h4.x,a0); a1=fmaf(fr[q].y,h4.y,a1);
                            a2=fmaf(fr[q].z,h4.z,a2); a3v=fmaf(fr[q].w,h4.w,a3v);
                        }
                        float t = (a0+a1)+(a2+a3v);
                        if (lane < RS) t_s[(base+m)*RS + lane] = t;
                    }
                }
            }
            __syncthreads();

            // ---- A[pair] for both elements: lanes (g*32+p), p<15 ----
            float av = 0.f;
            if (p < 15) {
                unsigned dng = g ? dn1 : dn0;
                int sn = (int)((dng>>pn)&1), sm = (int)((dng>>pm)&1);
                int hrow, trow; float sg;
                if (sn == sm)      { hrow = pn; trow = pm;     sg =  1.f; }
                else if (sn == 0)  { hrow = pn; trow = 6 + pm; sg =  1.f; }
                else               { hrow = pm; trow = 6 + pn; sg = -1.f; }
                const float4* hp = (const float4*)(hA  + (g*6 + hrow)*RS);
                const float4* tp = (const float4*)(t_s + (g*12 + trow)*RS);
                float a0=0.f,a1=0.f,a2=0.f,a3v=0.f;
                #pragma unroll
                for (int q=0;q<11;q++){
                    float4 hv = hp[q]; float4 tv = tp[q];
                    a0=fmaf(hv.x,tv.x,a0); a1=fmaf(hv.y,tv.y,a1);
                    a2=fmaf(hv.z,tv.z,a2); a3v=fmaf(hv.w,tv.w,a3v);
                }
                av = sg * ((a0+a1)+(a2+a3v));
            }
            // matching products + 16-lane group reduce, in registers
            int g32 = lane & 32;
            float q1 = __shfl(av, g32 + m1i);
            float q2 = __shfl(av, g32 + m2i);
            float q3 = __shfl(av, g32 + m3i);
            float term = 0.f;
            if (p < 15) { float pr = q1*q2*q3; term = (p & 1) ? -pr : pr; }
            term += __shfl_xor(term, 1);
            term += __shfl_xor(term, 2);
            term += __shfl_xor(term, 4);
            term += __shfl_xor(term, 8);
            total = fmaf(wreg[k], term, total);
            __syncthreads();
        }

        if (p == 0) {
            int e = e0 + g;
            float sgn = (total > 0.f) ? 1.f : ((total < 0.f) ? -1.f : 1.f);
            out[e]         = sgn;
            out[B_TOT + e] = 0.5f * logf(fmaf(total, total, 1e-60f));
        }
    }
}

extern "C" void kernel_launch(void* const* d_in, const int* in_sizes, int n_in,
                              void* d_out, int out_size, void* d_ws, size_t ws_size,
                              hipStream_t stream)
{
    const float* x    = (const float*)d_in[0];
    const int*   spin = (const int*)  d_in[1];
    const float* se   = (const float*)d_in[2];
    const float* W1   = (const float*)d_in[3];
    const float* b1   = (const float*)d_in[4];
    const float* W2   = (const float*)d_in[5];
    const float* b2   = (const float*)d_in[6];
    const float* W3   = (const float*)d_in[7];
    const float* b3   = (const float*)d_in[8];
    const float* Phf  = (const float*)d_in[9];
    const float* dFud = (const float*)d_in[10];
    const float* dFuu = (const float*)d_in[11];
    const float* dFdd = (const float*)d_in[12];
    const float* w    = (const float*)d_in[13];
    float* out = (float*)d_out;
    float4* wsF = (float4*)d_ws;   // 12*11*64 float4 = 135168 B

    hipLaunchKernelGGL(prep_F, dim3(33), dim3(256), 0, stream,
                       dFud, dFuu, dFdd, Phf, wsF);
    hipLaunchKernelGGL(pfaff_main, dim3(512), dim3(512), 0, stream,
                       x, spin, se, W1, b1, W2, b2, W3, b3, w, wsF, out);
}

// Round 4
// 537.479 us; speedup vs baseline: 1.5814x; 1.0832x over previous
//
#include <hip/hip_runtime.h>

#define B_TOT 65536
#define RS 44            // padded row stride (floats) for h / t rows
#define KDET 4

// ---- LDS float-offset layout (weights + per-wave scratch) ----
#define OFF_W1   0        // 640
#define OFF_B1   640      // 64
#define OFF_W2T  704      // 64*68 = 4352 (W2 transposed, rows padded to 68)
#define OFF_B2   5056     // 64
#define OFF_W3T  5120     // 32*68 = 2176 (W3 transposed, rows padded to 68)
#define OFF_B3   7296     // 32
#define OFF_SE   7328     // 16
#define OFF_SC   7344     // per-wave scratch
#define SC_STRIDE 1584    // t_s [0,1056): 24 rows*44 (time-shares h1 [128,896)) | hA [1056,1584)
#define LDS_FLOATS (7344 + 8*1584)   // 20016 floats = 80064 B -> 2 blocks/CU

// pair enumeration p=0..14 : (n,m) lexicographic n<m
__device__ const int PN_TAB[15] = {0,0,0,0,0,1,1,1,1,2,2,2,3,3,4};
__device__ const int PM_TAB[15] = {1,2,3,4,5,2,3,4,5,3,4,5,4,5,5};
// matchings -> 3 pair indices; sign alternates +,-,+,...
__device__ const int M1_TAB[15] = {0,0,0,1,1,1,2,2,2,3,3,3,4,4,4};
__device__ const int M2_TAB[15] = {9,10,11,6,7,8,5,7,8,5,6,8,5,6,7};
__device__ const int M3_TAB[15] = {14,13,12,14,13,12,14,11,10,13,11,9,12,10,9};

__device__ __forceinline__ float bcastf(float v, int l) {
    return __int_as_float(__builtin_amdgcn_readlane(__float_as_int(v), l));
}
#define WFENCE() __threadfence_block()

// Build F~ swizzled: wsF[(sk*11 + c)*64 + d] = float4 { F~[sk][d][4c+j] } j=0..3
// sk = s*4+k ; s: 0=uu 1=dd 2=ud. Rows d>=41, cols e>=41 zero.
__global__ void prep_F(const float* __restrict__ dFud, const float* __restrict__ dFuu,
                       const float* __restrict__ dFdd, const float* __restrict__ Phf,
                       float4* __restrict__ wsF)
{
    int t = blockIdx.x * 256 + threadIdx.x;
    if (t >= 12*11*64) return;
    int d  = t & 63;
    int c  = (t >> 6) % 11;
    int sk = t / (11*64);
    int s = sk >> 2, k = sk & 3;
    const float* src = (s==0) ? dFuu : (s==1) ? dFdd : dFud;
    float v[4];
    #pragma unroll
    for (int j=0;j<4;j++){
        int e = 4*c + j;
        float r = 0.f;
        if (d < 41 && e < 41) {
            if (s < 2) r = 0.01f * (src[(k*41+d)*41+e] - src[(k*41+e)*41+d]);
            else     { r = 0.01f *  src[(k*41+d)*41+e]; if (k==0) r += Phf[d*41+e]; }
        }
        v[j] = r;
    }
    wsF[t] = make_float4(v[0],v[1],v[2],v[3]);
}

__global__ __launch_bounds__(512, 4)
void pfaff_main(const float* __restrict__ x, const int* __restrict__ spin,
                const float* __restrict__ se, const float* __restrict__ W1,
                const float* __restrict__ b1, const float* __restrict__ W2,
                const float* __restrict__ b2, const float* __restrict__ W3,
                const float* __restrict__ b3, const float* __restrict__ wdet,
                const float4* __restrict__ wsF, float* __restrict__ out)
{
    __shared__ __align__(16) float lds[LDS_FLOATS];
    float* W1l  = lds + OFF_W1;
    float* b1l  = lds + OFF_B1;
    float* W2tl = lds + OFF_W2T;
    float* b2l  = lds + OFF_B2;
    float* W3tl = lds + OFF_W3T;
    float* b3l  = lds + OFF_B3;
    float* sel  = lds + OFF_SE;

    const int tid = threadIdx.x;

    for (int i = tid; i < 640;  i += blockDim.x) W1l[i] = W1[i];
    for (int i = tid; i < 64;   i += blockDim.x) b1l[i] = b1[i];
    for (int idx = tid; idx < 64*68; idx += blockDim.x) {
        int j = idx / 68, i = idx - j*68;
        W2tl[idx] = (i < 64) ? W2[i*64 + j] : 0.f;
    }
    for (int i = tid; i < 64;   i += blockDim.x) b2l[i] = b2[i];
    for (int idx = tid; idx < 32*68; idx += blockDim.x) {
        int j = idx / 68, i = idx - j*68;
        W3tl[idx] = (i < 64) ? W3[i*32 + j] : 0.f;
    }
    for (int i = tid; i < 32;   i += blockDim.x) b3l[i] = b3[i];
    for (int i = tid; i < 16;   i += blockDim.x) sel[i] = se[i];

    const int wave = tid >> 6, lane = tid & 63;
    float* sc  = lds + OFF_SC + wave*SC_STRIDE;
    float* t_s = sc;            // [0,1056)
    float* h1  = sc + 128;      // [128,896) (time-shared with t_s)
    float* hA  = sc + 1056;     // [1056,1584)

    for (int i = lane; i < SC_STRIDE; i += 64) sc[i] = 0.f;
    __syncthreads();   // weights visible; scratch clean

    // ---- per-lane persistent preloads ----
    float w1c[10];
    #pragma unroll
    for (int i=0;i<10;i++) w1c[i] = W1l[i*64 + lane];
    const float b1r = b1l[lane];
    const float b2r = b2l[lane];
    const float b3r = b3l[lane & 31];
    float emb0 = 0.f, emb1 = 0.f;
    #pragma unroll
    for (int j=0;j<8;j++){
        emb0 = fmaf(w1c[2+j], sel[j],   emb0);
        emb1 = fmaf(w1c[2+j], sel[8+j], emb1);
    }
    int pn=0, pm=0, m1i=0, m2i=0, m3i=0;
    const int p = lane & 31, g = lane >> 5;
    if (p < 15) { pn=PN_TAB[p]; pm=PM_TAB[p];
                  m1i=M1_TAB[p]; m2i=M2_TAB[p]; m3i=M3_TAB[p]; }
    float wreg[4];
    #pragma unroll
    for (int k=0;k<4;k++) wreg[k] = wdet[k];
    const int le = (lane < 44) ? lane : 43;   // clamped hreg read col

    const int ebase = ((int)blockIdx.x * 8 + wave) * 16;
    #pragma unroll 1
    for (int pi = 0; pi < 8; ++pi) {
        const int e0 = ebase + pi*2;

        // ---- P0: particle data for 2 elements; Phi -> hA rows ----
        int s_n = 0; float xx = 0.f, xy = 0.f;
        if (lane < 12) {
            int gg = lane >= 6;
            int eg = e0 + gg;
            int n  = lane - gg*6;
            float2 xv = *(const float2*)(x + (size_t)(eg*6 + n)*2);
            xx = xv.x; xy = xv.y;
            s_n = spin[eg*6 + n];
        }
        unsigned long long bal = __ballot(lane < 12 && s_n == 1);
        const unsigned dn0 = (unsigned)bal & 63u;
        const unsigned dn1 = (unsigned)(bal >> 6) & 63u;

        if (lane < 12) {
            float ex = __expf(-0.5f*(xx*xx));
            float px0 = 0.7511255444649425f * ex;
            float px1 = 1.4142135623730951f * xx * px0;
            float px2 = fmaf(xx, px1, -0.7071067811865476f * px0);
            float ey = __expf(-0.5f*(xy*xy));
            float py0 = 0.7511255444649425f * ey;
            float py1 = 1.4142135623730951f * xy * py0;
            float py2 = fmaf(xy, py1, -0.7071067811865476f * py0);
            float* hr = hA + lane*RS;
            hr[0]=px0*py0; hr[1]=px0*py1; hr[2]=px0*py2;
            hr[3]=px1*py0; hr[4]=px1*py1; hr[5]=px1*py2;
            hr[6]=px2*py0; hr[7]=px2*py1; hr[8]=px2*py2;
            hr[41]=0.f; hr[42]=0.f; hr[43]=0.f;
        }
        // ---- L1 (10->64): pure registers via readlane; no LDS reads ----
        #pragma unroll
        for (int r=0;r<12;r++){
            float xr = bcastf(xx, r);
            float yr = bcastf(xy, r);
            int   sr = __builtin_amdgcn_readlane(s_n, r);
            float a  = fmaf(xr, w1c[0], b1r);
            a = fmaf(yr, w1c[1], a);
            a += sr ? emb1 : emb0;
            h1[r*64 + lane] = a / (1.f + __expf(-a));
        }
        WFENCE();

        // ---- L2 (64->64) ----
        float acc[12];
        #pragma unroll
        for (int r=0;r<12;r++) acc[r] = b2r;
        #pragma unroll
        for (int i4=0;i4<16;i4++){
            float4 w4 = *(const float4*)(W2tl + lane*68 + i4*4);
            #pragma unroll
            for (int r=0;r<12;r++){
                float4 h4 = *(const float4*)(h1 + r*64 + i4*4);
                acc[r]=fmaf(w4.x,h4.x,acc[r]); acc[r]=fmaf(w4.y,h4.y,acc[r]);
                acc[r]=fmaf(w4.z,h4.z,acc[r]); acc[r]=fmaf(w4.w,h4.w,acc[r]);
            }
        }
        WFENCE();          // all lanes' reads complete before overwrite
        #pragma unroll
        for (int r=0;r<12;r++){
            float v = acc[r];
            h1[r*64 + lane] = v / (1.f + __expf(-v));
        }
        WFENCE();

        // ---- L3 (64->32): half-wave per element ----
        {
            int j2 = lane & 31, hf = lane >> 5;
            float a3[6];
            #pragma unroll
            for (int rr=0;rr<6;rr++) a3[rr] = b3r;
            #pragma unroll
            for (int i4=0;i4<16;i4++){
                float4 w4 = *(const float4*)(W3tl + j2*68 + i4*4);
                #pragma unroll
                for (int rr=0;rr<6;rr++){
                    float4 h4 = *(const float4*)(h1 + (hf*6+rr)*64 + i4*4);
                    a3[rr]=fmaf(w4.x,h4.x,a3[rr]); a3[rr]=fmaf(w4.y,h4.y,a3[rr]);
                    a3[rr]=fmaf(w4.z,h4.z,a3[rr]); a3[rr]=fmaf(w4.w,h4.w,a3[rr]);
                }
            }
            #pragma unroll
            for (int rr=0;rr<6;rr++) hA[(hf*6+rr)*RS + 9 + j2] = a3[rr];
        }
        WFENCE();

        // ---- h rows into lane-distributed registers (lane = e) ----
        float hreg[12];
        #pragma unroll
        for (int r=0;r<12;r++) hreg[r] = hA[r*RS + le];

        // ---- bilinear + pfaffian ----
        float total = 0.f;
        #pragma unroll 1
        for (int k = 0; k < KDET; ++k) {
            #pragma unroll 1
            for (int pass=0; pass<3; ++pass) {
                const float4* Fp = wsF + (size_t)(pass*4 + k)*(11*64) + lane;
                float fr[44];
                #pragma unroll
                for (int c=0;c<11;c++){
                    float4 v = Fp[c*64];
                    fr[4*c]=v.x; fr[4*c+1]=v.y; fr[4*c+2]=v.z; fr[4*c+3]=v.w;
                }
                const int dstb = (pass==2) ? 6 : 0;
                #pragma unroll
                for (int gg=0; gg<2; ++gg){
                    const unsigned dng = gg ? dn1 : dn0;
                    const unsigned mk  = pass ? dng : ((~dng) & 63u);
                    #pragma unroll
                    for (int m=0;m<6;m++){
                        if ((mk>>m)&1) {
                            float a0=0.f, a1=0.f;
                            #pragma unroll
                            for (int e=0;e<40;e+=2){
                                a0 = fmaf(fr[e],   bcastf(hreg[gg*6+m], e),   a0);
                                a1 = fmaf(fr[e+1], bcastf(hreg[gg*6+m], e+1), a1);
                            }
                            a0 = fmaf(fr[40], bcastf(hreg[gg*6+m], 40), a0);
                            float t = a0 + a1;
                            if (lane < RS)
                                t_s[(gg*12 + dstb + m)*RS + lane] = (lane < 41) ? t : 0.f;
                        }
                    }
                }
            }
            WFENCE();

            // ---- A[pair] for both elements: lanes (g*32+p), p<15 ----
            float av = 0.f;
            if (p < 15) {
                unsigned dng = g ? dn1 : dn0;
                int sn = (int)((dng>>pn)&1), sm = (int)((dng>>pm)&1);
                int hrow, trow; float sg;
                if (sn == sm)      { hrow = pn; trow = pm;     sg =  1.f; }
                else if (sn == 0)  { hrow = pn; trow = 6 + pm; sg =  1.f; }
                else               { hrow = pm; trow = 6 + pn; sg = -1.f; }
                const float4* hp = (const float4*)(hA  + (g*6  + hrow)*RS);
                const float4* tp = (const float4*)(t_s + (g*12 + trow)*RS);
                float a0=0.f,a1=0.f,a2=0.f,a3v=0.f;
                #pragma unroll
                for (int q=0;q<11;q++){
                    float4 hv = hp[q]; float4 tv = tp[q];
                    a0=fmaf(hv.x,tv.x,a0); a1=fmaf(hv.y,tv.y,a1);
                    a2=fmaf(hv.z,tv.z,a2); a3v=fmaf(hv.w,tv.w,a3v);
                }
                av = sg * ((a0+a1)+(a2+a3v));
            }
            int g32 = lane & 32;
            float q1 = __shfl(av, g32 + m1i);
            float q2 = __shfl(av, g32 + m2i);
            float q3 = __shfl(av, g32 + m3i);
            float term = 0.f;
            if (p < 15) { float pr = q1*q2*q3; term = (p & 1) ? -pr : pr; }
            term += __shfl_xor(term, 1);
            term += __shfl_xor(term, 2);
            term += __shfl_xor(term, 4);
            term += __shfl_xor(term, 8);
            total = fmaf(wreg[k], term, total);
            WFENCE();   // A-dot reads done before next k's t stores
        }

        if (p == 0) {
            int e = e0 + g;
            float sgn = (total > 0.f) ? 1.f : ((total < 0.f) ? -1.f : 1.f);
            out[e]         = sgn;
            out[B_TOT + e] = 0.5f * logf(fmaf(total, total, 1e-60f));
        }
        WFENCE();       // t_s/h1 region free before next iter's writes
    }
}

extern "C" void kernel_launch(void* const* d_in, const int* in_sizes, int n_in,
                              void* d_out, int out_size, void* d_ws, size_t ws_size,
                              hipStream_t stream)
{
    const float* x    = (const float*)d_in[0];
    const int*   spin = (const int*)  d_in[1];
    const float* se   = (const float*)d_in[2];
    const float* W1   = (const float*)d_in[3];
    const float* b1   = (const float*)d_in[4];
    const float* W2   = (const float*)d_in[5];
    const float* b2   = (const float*)d_in[6];
    const float* W3   = (const float*)d_in[7];
    const float* b3   = (const float*)d_in[8];
    const float* Phf  = (const float*)d_in[9];
    const float* dFud = (const float*)d_in[10];
    const float* dFuu = (const float*)d_in[11];
    const float* dFdd = (const float*)d_in[12];
    const float* w    = (const float*)d_in[13];
    float* out = (float*)d_out;
    float4* wsF = (float4*)d_ws;   // 12*11*64 float4 = 135168 B

    hipLaunchKernelGGL(prep_F, dim3(33), dim3(256), 0, stream,
                       dFud, dFuu, dFdd, Phf, wsF);
    hipLaunchKernelGGL(pfaff_main, dim3(512), dim3(512), 0, stream,
                       x, spin, se, W1, b1, W2, b2, W3, b3, w, wsF, out);
}